// Round 4
// baseline (310.715 us; speedup 1.0000x reference)
//
#include <hip/hip_runtime.h>
#include <hip/hip_bf16.h>
#include <math.h>

#define NEMB 768
#define NH   12
#define HD   64
#define BSZ  4
#define SEQ  2048
#define MTOT (BSZ * SEQ)   // 8192

// scale folded into Q projection: (1/sqrt(768)) * log2(e)
#define SCALE_LOG2E 0.0520587833f

typedef short bf16x8 __attribute__((ext_vector_type(8)));   // 8 bf16 = 4 VGPR
typedef short short4v __attribute__((ext_vector_type(4)));
typedef float f32x4 __attribute__((ext_vector_type(4)));
typedef unsigned u32x4 __attribute__((ext_vector_type(4)));

// fp32 -> bf16 RNE via native conversion
__device__ __forceinline__ short f2bf(float f) {
  __bf16 h = (__bf16)f;
  return __builtin_bit_cast(short, h);
}

// async global->LDS, 16B per lane (linear LDS dest, per-lane global src)
__device__ __forceinline__ void g2l16(const short* g, short* l) {
  __builtin_amdgcn_global_load_lds((const __attribute__((address_space(1))) unsigned*)g,
                                   (__attribute__((address_space(3))) unsigned*)l, 16, 0, 0);
}

// XOR swizzle on 16B units within a 128B row (G4 / rule 21)
__device__ __forceinline__ int swz(int x) { return (x ^ (x >> 3)) & 7; }

// ---------------------------------------------------------------------------
// all fp32 -> bf16 converts in ONE dispatch (y = which array)
// ---------------------------------------------------------------------------
__global__ __launch_bounds__(256) void cvt_all(
    const float* __restrict__ i0, const float* __restrict__ i1, const float* __restrict__ i2,
    const float* __restrict__ i3, const float* __restrict__ i4, const float* __restrict__ i5,
    const float* __restrict__ i6,
    short* __restrict__ o0, short* __restrict__ o1, short* __restrict__ o2,
    short* __restrict__ o3, short* __restrict__ o4, short* __restrict__ o5,
    short* __restrict__ o6) {
  const int ACT4 = (MTOT * NEMB) / 4;   // 1572864
  const int WGT4 = (NEMB * NEMB) / 4;   // 147456
  const float* in; short* out; int n4;
  switch (blockIdx.y) {
    case 0: in = i0; out = o0; n4 = ACT4; break;
    case 1: in = i1; out = o1; n4 = ACT4; break;
    case 2: in = i2; out = o2; n4 = ACT4; break;
    case 3: in = i3; out = o3; n4 = WGT4; break;
    case 4: in = i4; out = o4; n4 = WGT4; break;
    case 5: in = i5; out = o5; n4 = WGT4; break;
    default: in = i6; out = o6; n4 = WGT4; break;
  }
  int i = blockIdx.x * 256 + threadIdx.x;
  if (i >= n4) return;
  float4 f = reinterpret_cast<const float4*>(in)[i];
  short4v s; s[0] = f2bf(f.x); s[1] = f2bf(f.y); s[2] = f2bf(f.z); s[3] = f2bf(f.w);
  reinterpret_cast<short4v*>(out)[i] = s;
}

// ---------------------------------------------------------------------------
// Fused Q/K/V projection GEMM, 2-phase pipelined (T3-minimum):
// stage(t+1 -> buf^1) issued BEFORE compute(buf), ONE barrier per K-step.
// 128x128 tile, BK=32, bf16 out; Q output pre-scaled by SCALE_LOG2E.
// ---------------------------------------------------------------------------
__global__ __launch_bounds__(256) void gemm_qkv(
    const short* __restrict__ A0, const short* __restrict__ A1, const short* __restrict__ A2,
    const short* __restrict__ W0, const short* __restrict__ W1, const short* __restrict__ W2,
    const float* __restrict__ b0, const float* __restrict__ b1, const float* __restrict__ b2,
    short* __restrict__ O0, short* __restrict__ O1, short* __restrict__ O2) {
  __shared__ __align__(16) short As[2][128 * 32];
  __shared__ __align__(16) short Bs[2][128 * 32];
  const short* A; const short* W; const float* bias; short* O; float scl;
  switch (blockIdx.z) {
    case 0:  A = A0; W = W0; bias = b0; O = O0; scl = SCALE_LOG2E; break;
    case 1:  A = A1; W = W1; bias = b1; O = O1; scl = 1.f; break;
    default: A = A2; W = W2; bias = b2; O = O2; scl = 1.f; break;
  }
  const int tid = threadIdx.x;
  const int lane = tid & 63, w = tid >> 6;
  const int wr = w >> 1, wc = w & 1;
  const int l15 = lane & 15, l4 = lane >> 4;
  const int m0 = blockIdx.x * 128, n0 = blockIdx.y * 128;

  f32x4 acc[4][4] = {};

  // prologue: stage K-step 0 into buf 0
#pragma unroll
  for (int i = 0; i < 2; ++i) {
    const int idx = tid + i * 256;          // 16B units (512/matrix)
    const int row = idx >> 2, u = idx & 3;  // 64B rows = 4 units
    g2l16(A + (size_t)(m0 + row) * NEMB + u * 8, &As[0][idx * 8]);
    g2l16(W + (size_t)(n0 + row) * NEMB + u * 8, &Bs[0][idx * 8]);
  }
  __syncthreads();

  const int NT = NEMB / 32;   // 24
  for (int t = 0; t < NT; ++t) {
    const int cur = t & 1;
    if (t + 1 < NT) {
      const int k0 = (t + 1) * 32;
#pragma unroll
      for (int i = 0; i < 2; ++i) {
        const int idx = tid + i * 256;
        const int row = idx >> 2, u = idx & 3;
        g2l16(A + (size_t)(m0 + row) * NEMB + k0 + u * 8, &As[cur ^ 1][idx * 8]);
        g2l16(W + (size_t)(n0 + row) * NEMB + k0 + u * 8, &Bs[cur ^ 1][idx * 8]);
      }
    }
    bf16x8 af[4], bfr[4];
#pragma unroll
    for (int m = 0; m < 4; ++m)
      af[m] = *reinterpret_cast<const bf16x8*>(&As[cur][(wr * 64 + m * 16 + l15) * 32 + l4 * 8]);
#pragma unroll
    for (int n = 0; n < 4; ++n)
      bfr[n] = *reinterpret_cast<const bf16x8*>(&Bs[cur][(wc * 64 + n * 16 + l15) * 32 + l4 * 8]);
#pragma unroll
    for (int m = 0; m < 4; ++m)
#pragma unroll
      for (int n = 0; n < 4; ++n)
        acc[m][n] = __builtin_amdgcn_mfma_f32_16x16x32_bf16(af[m], bfr[n], acc[m][n], 0, 0, 0);
    __syncthreads();   // drains this iter's staging + compute; buffers flip
  }

  float bj[4];
#pragma unroll
  for (int n = 0; n < 4; ++n) bj[n] = bias[n0 + wc * 64 + n * 16 + l15];
#pragma unroll
  for (int m = 0; m < 4; ++m)
#pragma unroll
    for (int n = 0; n < 4; ++n) {
      const int col = n0 + wc * 64 + n * 16 + l15;
#pragma unroll
      for (int r = 0; r < 4; ++r) {
        const int row = m0 + wr * 64 + m * 16 + l4 * 4 + r;
        O[(size_t)row * NEMB + col] = f2bf((acc[m][n][r] + bj[n]) * scl);
      }
    }
}

// ---------------------------------------------------------------------------
// FC GEMM: 128x64 tile (grid 64x12=768 -> 3 blocks/CU even), 2-phase, f32 out.
// 4 waves: wave w owns rows w*32..w*32+31, all 64 cols (acc[2][4]).
// ---------------------------------------------------------------------------
__global__ __launch_bounds__(256) void gemm_fc(
    const short* __restrict__ A, const short* __restrict__ W,
    const float* __restrict__ bias, float* __restrict__ C) {
  __shared__ __align__(16) short As[2][128 * 32];
  __shared__ __align__(16) short Bs[2][64 * 32];
  const int tid = threadIdx.x;
  const int lane = tid & 63, w = tid >> 6;
  const int l15 = lane & 15, l4 = lane >> 4;
  const int m0 = blockIdx.x * 128, n0 = blockIdx.y * 64;

  f32x4 acc[2][4] = {};

  // prologue: stage K-step 0
#pragma unroll
  for (int i = 0; i < 2; ++i) {
    const int idx = tid + i * 256;
    const int row = idx >> 2, u = idx & 3;
    g2l16(A + (size_t)(m0 + row) * NEMB + u * 8, &As[0][idx * 8]);
  }
  {
    const int row = tid >> 2, u = tid & 3;  // 256 units for 64x32 B tile
    g2l16(W + (size_t)(n0 + row) * NEMB + u * 8, &Bs[0][tid * 8]);
  }
  __syncthreads();

  const int NT = NEMB / 32;
  for (int t = 0; t < NT; ++t) {
    const int cur = t & 1;
    if (t + 1 < NT) {
      const int k0 = (t + 1) * 32;
#pragma unroll
      for (int i = 0; i < 2; ++i) {
        const int idx = tid + i * 256;
        const int row = idx >> 2, u = idx & 3;
        g2l16(A + (size_t)(m0 + row) * NEMB + k0 + u * 8, &As[cur ^ 1][idx * 8]);
      }
      const int row = tid >> 2, u = tid & 3;
      g2l16(W + (size_t)(n0 + row) * NEMB + k0 + u * 8, &Bs[cur ^ 1][tid * 8]);
    }
    bf16x8 af[2], bfr[4];
#pragma unroll
    for (int m = 0; m < 2; ++m)
      af[m] = *reinterpret_cast<const bf16x8*>(&As[cur][(w * 32 + m * 16 + l15) * 32 + l4 * 8]);
#pragma unroll
    for (int n = 0; n < 4; ++n)
      bfr[n] = *reinterpret_cast<const bf16x8*>(&Bs[cur][(n * 16 + l15) * 32 + l4 * 8]);
#pragma unroll
    for (int m = 0; m < 2; ++m)
#pragma unroll
      for (int n = 0; n < 4; ++n)
        acc[m][n] = __builtin_amdgcn_mfma_f32_16x16x32_bf16(af[m], bfr[n], acc[m][n], 0, 0, 0);
    __syncthreads();
  }

  float bj[4];
#pragma unroll
  for (int n = 0; n < 4; ++n) bj[n] = bias[n0 + n * 16 + l15];
#pragma unroll
  for (int m = 0; m < 2; ++m)
#pragma unroll
    for (int n = 0; n < 4; ++n) {
      const int col = n0 + n * 16 + l15;
#pragma unroll
      for (int r = 0; r < 4; ++r) {
        const int row = m0 + w * 32 + m * 16 + l4 * 4 + r;
        C[(size_t)row * NEMB + col] = acc[m][n][r] + bj[n];
      }
    }
}

// ---------------------------------------------------------------------------
// MFMA flash attention v3: QBLK=128 (8 waves, 512 thr), KVBLK=64,
// double-buffered K/Vt, ONE barrier/iter, wave-specialized staging:
//   waves 0-3: K(t+1) via global_load_lds (inverse-swizzled source)
//   waves 4-7: V(t+1) reg-load early (T14), perm-pack, swizzled LDS write late
// Softmax: p = exp2(S') (scale pre-folded into Q projection).
// Grid: 768 = 8 XCDs x 96, bijective chunk; 3 blocks/CU = full residency.
// ---------------------------------------------------------------------------
__global__ __launch_bounds__(512) void attn_mfma(const short* __restrict__ qp, const short* __restrict__ kp,
                                                 const short* __restrict__ vp, short* __restrict__ ao) {
  __shared__ __align__(16) short Ks[2][64 * 64];
  __shared__ __align__(16) short Vt[2][64 * 64];
  __shared__ __align__(16) short Ps[8][16 * 72];
  const int tid = threadIdx.x, lane = tid & 63, w = tid >> 6;
  const int l15 = lane & 15, l4 = lane >> 4;
  // bijective XCD chunking: 768 wgs = 8 XCDs x 96; consecutive nid share (b,h)
  const int wg = blockIdx.x;
  const int nid = (wg & 7) * 96 + (wg >> 3);
  const int q0 = (nid & 15) * 128;
  const int bh = nid >> 4;
  const int b = bh / NH, h = bh - b * NH;
  const size_t abase = (size_t)b * SEQ * NEMB + h * HD;

  // Q fragments (pre-scaled in projection), global->reg once (16 q-rows/wave)
  bf16x8 qf[2];
#pragma unroll
  for (int kb = 0; kb < 2; ++kb)
    qf[kb] = *reinterpret_cast<const bf16x8*>(
        &qp[abase + (size_t)(q0 + w * 16 + l15) * NEMB + kb * 32 + l4 * 8]);

  const bool kstager = (w < 4);
  const int st = tid & 255;                 // staging lane id within role group
  const int vkv2 = st >> 3, vd8 = st & 7;   // V: 32 row-pairs x 8 d-units
  const int vu = vkv2 >> 2, vsub = vkv2 & 3;
  const int pch = l15 >> 3, pcl = l15 & 7;  // P-write col split

  // ---- prologue: stage tile 0 into buf 0 ----
  if (kstager) {
#pragma unroll
    for (int i = 0; i < 2; ++i) {
      const int idx = st + i * 256;         // 512 16B units; 8 per 128B row
      const int row = idx >> 3, u = idx & 7;
      g2l16(kp + abase + (size_t)row * NEMB + (u ^ swz(row)) * 8, &Ks[0][idx * 8]);
    }
  } else {
    const short* vr = vp + abase + (size_t)(vkv2 * 2) * NEMB + vd8 * 8;
    bf16x8 v0 = *reinterpret_cast<const bf16x8*>(vr);
    bf16x8 v1 = *reinterpret_cast<const bf16x8*>(vr + NEMB);
    u32x4 a0 = __builtin_bit_cast(u32x4, v0);
    u32x4 a1 = __builtin_bit_cast(u32x4, v1);
#pragma unroll
    for (int jj = 0; jj < 4; ++jj) {
      unsigned lo = __builtin_amdgcn_perm(a1[jj], a0[jj], 0x05040100u);
      unsigned hi = __builtin_amdgcn_perm(a1[jj], a0[jj], 0x07060302u);
      const int d0 = vd8 * 8 + jj * 2;
      *reinterpret_cast<unsigned*>(reinterpret_cast<char*>(Vt[0]) + d0 * 128 + (vu ^ swz(d0)) * 16 + vsub * 4) = lo;
      *reinterpret_cast<unsigned*>(reinterpret_cast<char*>(Vt[0]) + (d0 + 1) * 128 + (vu ^ swz(d0 + 1)) * 16 + vsub * 4) = hi;
    }
  }
  __syncthreads();

  f32x4 o[4] = {};
  float lacc[4] = {0.f, 0.f, 0.f, 0.f};

  for (int kt = 0; kt < SEQ / 64; ++kt) {
    const int cur = kt & 1, nxt = cur ^ 1;
    const bool more = (kt + 1) < SEQ / 64;

    // ---- issue staging for tile kt+1 (hidden under this tile's compute) ----
    bf16x8 v0, v1;
    if (kstager) {
      if (more) {
#pragma unroll
        for (int i = 0; i < 2; ++i) {
          const int idx = st + i * 256;
          const int row = idx >> 3, u = idx & 7;
          g2l16(kp + abase + (size_t)((kt + 1) * 64 + row) * NEMB + (u ^ swz(row)) * 8,
                &Ks[nxt][idx * 8]);
        }
      }
    } else if (more) {
      const short* vr = vp + abase + (size_t)((kt + 1) * 64 + vkv2 * 2) * NEMB + vd8 * 8;
      v0 = *reinterpret_cast<const bf16x8*>(vr);
      v1 = *reinterpret_cast<const bf16x8*>(vr + NEMB);
    }

    // ---- S = Q K^T from Ks[cur] ----
    f32x4 sf[4];
#pragma unroll
    for (int nf = 0; nf < 4; ++nf) {
      f32x4 a = {0.f, 0.f, 0.f, 0.f};
#pragma unroll
      for (int kb = 0; kb < 2; ++kb) {
        const int row = nf * 16 + l15;
        const int u = kb * 4 + l4;
        bf16x8 kf = *reinterpret_cast<const bf16x8*>(
            reinterpret_cast<char*>(Ks[cur]) + row * 128 + (u ^ swz(row)) * 16);
        a = __builtin_amdgcn_mfma_f32_16x16x32_bf16(qf[kb], kf, a, 0, 0, 0);
      }
      sf[nf] = a;
    }

    // ---- softmax: p = exp2(S'); swizzled P store (per-wave buffer) ----
#pragma unroll
    for (int nf = 0; nf < 4; ++nf)
#pragma unroll
      for (int r = 0; r < 4; ++r) {
        const float p = exp2f(sf[nf][r]);
        lacc[r] += p;
        Ps[w][(l4 * 4 + r) * 72 + (((nf * 2 + pch) ^ l4) << 3) + pcl] = f2bf(p);
      }

    // ---- late Vt write for tile kt+1 (loads have drained under QK/softmax) ----
    if (!kstager && more) {
      u32x4 a0 = __builtin_bit_cast(u32x4, v0);
      u32x4 a1 = __builtin_bit_cast(u32x4, v1);
#pragma unroll
      for (int jj = 0; jj < 4; ++jj) {
        unsigned lo = __builtin_amdgcn_perm(a1[jj], a0[jj], 0x05040100u);
        unsigned hi = __builtin_amdgcn_perm(a1[jj], a0[jj], 0x07060302u);
        const int d0 = vd8 * 8 + jj * 2;
        *reinterpret_cast<unsigned*>(reinterpret_cast<char*>(Vt[nxt]) + d0 * 128 + (vu ^ swz(d0)) * 16 + vsub * 4) = lo;
        *reinterpret_cast<unsigned*>(reinterpret_cast<char*>(Vt[nxt]) + (d0 + 1) * 128 + (vu ^ swz(d0 + 1)) * 16 + vsub * 4) = hi;
      }
    }

    // ---- O += P V from Vt[cur] ----
#pragma unroll
    for (int kb = 0; kb < 2; ++kb) {
      bf16x8 pf = *reinterpret_cast<const bf16x8*>(
          &Ps[w][l15 * 72 + (((kb * 4 + l4) ^ ((l15 >> 2) & 3)) << 3)]);
#pragma unroll
      for (int df = 0; df < 4; ++df) {
        const int d = df * 16 + l15;
        const int u = kb * 4 + l4;
        bf16x8 vf = *reinterpret_cast<const bf16x8*>(
            reinterpret_cast<char*>(Vt[cur]) + d * 128 + (u ^ swz(d)) * 16);
        o[df] = __builtin_amdgcn_mfma_f32_16x16x32_bf16(pf, vf, o[df], 0, 0, 0);
      }
    }
    __syncthreads();   // single drain+barrier per iter; buffers flip
  }

  // full row-sums: reduce over the 16 kv-lanes (l15 bits)
#pragma unroll
  for (int r = 0; r < 4; ++r)
#pragma unroll
    for (int off = 1; off < 16; off <<= 1)
      lacc[r] += __shfl_xor(lacc[r], off, 64);

  float inv[4];
#pragma unroll
  for (int r = 0; r < 4; ++r) inv[r] = 1.f / lacc[r];

#pragma unroll
  for (int df = 0; df < 4; ++df)
#pragma unroll
    for (int r = 0; r < 4; ++r) {
      const int row = q0 + w * 16 + l4 * 4 + r;
      ao[abase + (size_t)row * NEMB + df * 16 + l15] = f2bf(o[df][r] * inv[r]);
    }
}

// ---------------------------------------------------------------------------
extern "C" void kernel_launch(void* const* d_in, const int* in_sizes, int n_in,
                              void* d_out, int out_size, void* d_ws, size_t ws_size,
                              hipStream_t stream) {
  const float* key   = (const float*)d_in[0];
  const float* query = (const float*)d_in[1];
  const float* value = (const float*)d_in[2];
  const float* Wk    = (const float*)d_in[3];
  const float* bk    = (const float*)d_in[4];
  const float* Wq    = (const float*)d_in[5];
  const float* bq    = (const float*)d_in[6];
  const float* Wv    = (const float*)d_in[7];
  const float* bv    = (const float*)d_in[8];
  const float* Wfc   = (const float*)d_in[9];
  const float* bfc   = (const float*)d_in[10];

  const size_t P = (size_t)MTOT * NEMB;   // 6,291,456
  const size_t WSZ = (size_t)NEMB * NEMB; // 589,824
  short* ws  = (short*)d_ws;
  short* qb  = ws;
  short* kb2 = qb + P;
  short* vb2 = kb2 + P;
  short* wq  = vb2 + P;
  short* wk  = wq + WSZ;
  short* wv  = wk + WSZ;
  short* wf  = wv + WSZ;
  short* qpp = wf + WSZ;
  short* kpp = qpp + P;
  short* vpp = kpp + P;
  short* aop = vpp + P;

  cvt_all<<<dim3(P / 4 / 256, 7), 256, 0, stream>>>(
      query, key, value, Wq, Wk, Wv, Wfc, qb, kb2, vb2, wq, wk, wv, wf);

  gemm_qkv<<<dim3(MTOT / 128, NEMB / 128, 3), 256, 0, stream>>>(
      qb, kb2, vb2, wq, wk, wv, bq, bk, bv, qpp, kpp, vpp);

  attn_mfma<<<dim3(16 * BSZ * NH), 512, 0, stream>>>(qpp, kpp, vpp, aop);

  gemm_fc<<<dim3(MTOT / 128, NEMB / 64), 256, 0, stream>>>(aop, wf, bfc, (float*)d_out);
}

// Round 5
// 285.360 us; speedup vs baseline: 1.0889x; 1.0889x over previous
//
#include <hip/hip_runtime.h>
#include <hip/hip_bf16.h>
#include <math.h>

#define NEMB 768
#define NH   12
#define HD   64
#define BSZ  4
#define SEQ  2048
#define MTOT (BSZ * SEQ)   // 8192

// scale folded into Q projection: (1/sqrt(768)) * log2(e)
#define SCALE_LOG2E 0.0520587833f

typedef short bf16x8 __attribute__((ext_vector_type(8)));   // 8 bf16 = 4 VGPR
typedef short short4v __attribute__((ext_vector_type(4)));
typedef float f32x4 __attribute__((ext_vector_type(4)));
typedef float f32x16 __attribute__((ext_vector_type(16)));
typedef unsigned u32x4 __attribute__((ext_vector_type(4)));

// fp32 -> bf16 RNE via native conversion
__device__ __forceinline__ short f2bf(float f) {
  __bf16 h = (__bf16)f;
  return __builtin_bit_cast(short, h);
}

// async global->LDS, 16B per lane (linear LDS dest, per-lane global src)
__device__ __forceinline__ void g2l16(const short* g, short* l) {
  __builtin_amdgcn_global_load_lds((const __attribute__((address_space(1))) unsigned*)g,
                                   (__attribute__((address_space(3))) unsigned*)l, 16, 0, 0);
}

// XOR swizzle on 16B units within a 128B row (G4 / rule 21)
__device__ __forceinline__ int swz(int x) { return (x ^ (x >> 3)) & 7; }

// ---------------------------------------------------------------------------
// all fp32 -> bf16 converts in ONE dispatch (y = which array)
// ---------------------------------------------------------------------------
__global__ __launch_bounds__(256) void cvt_all(
    const float* __restrict__ i0, const float* __restrict__ i1, const float* __restrict__ i2,
    const float* __restrict__ i3, const float* __restrict__ i4, const float* __restrict__ i5,
    const float* __restrict__ i6,
    short* __restrict__ o0, short* __restrict__ o1, short* __restrict__ o2,
    short* __restrict__ o3, short* __restrict__ o4, short* __restrict__ o5,
    short* __restrict__ o6) {
  const int ACT4 = (MTOT * NEMB) / 4;   // 1572864
  const int WGT4 = (NEMB * NEMB) / 4;   // 147456
  const float* in; short* out; int n4;
  switch (blockIdx.y) {
    case 0: in = i0; out = o0; n4 = ACT4; break;
    case 1: in = i1; out = o1; n4 = ACT4; break;
    case 2: in = i2; out = o2; n4 = ACT4; break;
    case 3: in = i3; out = o3; n4 = WGT4; break;
    case 4: in = i4; out = o4; n4 = WGT4; break;
    case 5: in = i5; out = o5; n4 = WGT4; break;
    default: in = i6; out = o6; n4 = WGT4; break;
  }
  int i = blockIdx.x * 256 + threadIdx.x;
  if (i >= n4) return;
  float4 f = reinterpret_cast<const float4*>(in)[i];
  short4v s; s[0] = f2bf(f.x); s[1] = f2bf(f.y); s[2] = f2bf(f.z); s[3] = f2bf(f.w);
  reinterpret_cast<short4v*>(out)[i] = s;
}

// ---------------------------------------------------------------------------
// Fused Q/K/V projection GEMM, 2-phase pipelined; m97 structure (16x16x32:
// GEMM has 4x reg-reuse of frags so 16x16 is operand-optimal here).
// ---------------------------------------------------------------------------
__global__ __launch_bounds__(256) void gemm_qkv(
    const short* __restrict__ A0, const short* __restrict__ A1, const short* __restrict__ A2,
    const short* __restrict__ W0, const short* __restrict__ W1, const short* __restrict__ W2,
    const float* __restrict__ b0, const float* __restrict__ b1, const float* __restrict__ b2,
    short* __restrict__ O0, short* __restrict__ O1, short* __restrict__ O2) {
  __shared__ __align__(16) short As[2][128 * 32];
  __shared__ __align__(16) short Bs[2][128 * 32];
  const short* A; const short* W; const float* bias; short* O; float scl;
  switch (blockIdx.z) {
    case 0:  A = A0; W = W0; bias = b0; O = O0; scl = SCALE_LOG2E; break;
    case 1:  A = A1; W = W1; bias = b1; O = O1; scl = 1.f; break;
    default: A = A2; W = W2; bias = b2; O = O2; scl = 1.f; break;
  }
  const int tid = threadIdx.x;
  const int lane = tid & 63, w = tid >> 6;
  const int wr = w >> 1, wc = w & 1;
  const int l15 = lane & 15, l4 = lane >> 4;
  const int m0 = blockIdx.x * 128, n0 = blockIdx.y * 128;

  f32x4 acc[4][4] = {};

#pragma unroll
  for (int i = 0; i < 2; ++i) {
    const int idx = tid + i * 256;
    const int row = idx >> 2, u = idx & 3;
    g2l16(A + (size_t)(m0 + row) * NEMB + u * 8, &As[0][idx * 8]);
    g2l16(W + (size_t)(n0 + row) * NEMB + u * 8, &Bs[0][idx * 8]);
  }
  __syncthreads();

  const int NT = NEMB / 32;   // 24
  for (int t = 0; t < NT; ++t) {
    const int cur = t & 1;
    if (t + 1 < NT) {
      const int k0 = (t + 1) * 32;
#pragma unroll
      for (int i = 0; i < 2; ++i) {
        const int idx = tid + i * 256;
        const int row = idx >> 2, u = idx & 3;
        g2l16(A + (size_t)(m0 + row) * NEMB + k0 + u * 8, &As[cur ^ 1][idx * 8]);
        g2l16(W + (size_t)(n0 + row) * NEMB + k0 + u * 8, &Bs[cur ^ 1][idx * 8]);
      }
    }
    bf16x8 af[4], bfr[4];
#pragma unroll
    for (int m = 0; m < 4; ++m)
      af[m] = *reinterpret_cast<const bf16x8*>(&As[cur][(wr * 64 + m * 16 + l15) * 32 + l4 * 8]);
#pragma unroll
    for (int n = 0; n < 4; ++n)
      bfr[n] = *reinterpret_cast<const bf16x8*>(&Bs[cur][(wc * 64 + n * 16 + l15) * 32 + l4 * 8]);
#pragma unroll
    for (int m = 0; m < 4; ++m)
#pragma unroll
      for (int n = 0; n < 4; ++n)
        acc[m][n] = __builtin_amdgcn_mfma_f32_16x16x32_bf16(af[m], bfr[n], acc[m][n], 0, 0, 0);
    __syncthreads();
  }

  float bj[4];
#pragma unroll
  for (int n = 0; n < 4; ++n) bj[n] = bias[n0 + wc * 64 + n * 16 + l15];
#pragma unroll
  for (int m = 0; m < 4; ++m)
#pragma unroll
    for (int n = 0; n < 4; ++n) {
      const int col = n0 + wc * 64 + n * 16 + l15;
#pragma unroll
      for (int r = 0; r < 4; ++r) {
        const int row = m0 + wr * 64 + m * 16 + l4 * 4 + r;
        O[(size_t)row * NEMB + col] = f2bf((acc[m][n][r] + bj[n]) * scl);
      }
    }
}

// ---------------------------------------------------------------------------
// FC GEMM: 128x64 tile, 2-phase, f32 out (grid 64x12=768 -> 3 blocks/CU even)
// ---------------------------------------------------------------------------
__global__ __launch_bounds__(256) void gemm_fc(
    const short* __restrict__ A, const short* __restrict__ W,
    const float* __restrict__ bias, float* __restrict__ C) {
  __shared__ __align__(16) short As[2][128 * 32];
  __shared__ __align__(16) short Bs[2][64 * 32];
  const int tid = threadIdx.x;
  const int lane = tid & 63, w = tid >> 6;
  const int l15 = lane & 15, l4 = lane >> 4;
  const int m0 = blockIdx.x * 128, n0 = blockIdx.y * 64;

  f32x4 acc[2][4] = {};

#pragma unroll
  for (int i = 0; i < 2; ++i) {
    const int idx = tid + i * 256;
    const int row = idx >> 2, u = idx & 3;
    g2l16(A + (size_t)(m0 + row) * NEMB + u * 8, &As[0][idx * 8]);
  }
  {
    const int row = tid >> 2, u = tid & 3;
    g2l16(W + (size_t)(n0 + row) * NEMB + u * 8, &Bs[0][tid * 8]);
  }
  __syncthreads();

  const int NT = NEMB / 32;
  for (int t = 0; t < NT; ++t) {
    const int cur = t & 1;
    if (t + 1 < NT) {
      const int k0 = (t + 1) * 32;
#pragma unroll
      for (int i = 0; i < 2; ++i) {
        const int idx = tid + i * 256;
        const int row = idx >> 2, u = idx & 3;
        g2l16(A + (size_t)(m0 + row) * NEMB + k0 + u * 8, &As[cur ^ 1][idx * 8]);
      }
      const int row = tid >> 2, u = tid & 3;
      g2l16(W + (size_t)(n0 + row) * NEMB + k0 + u * 8, &Bs[cur ^ 1][tid * 8]);
    }
    bf16x8 af[2], bfr[4];
#pragma unroll
    for (int m = 0; m < 2; ++m)
      af[m] = *reinterpret_cast<const bf16x8*>(&As[cur][(w * 32 + m * 16 + l15) * 32 + l4 * 8]);
#pragma unroll
    for (int n = 0; n < 4; ++n)
      bfr[n] = *reinterpret_cast<const bf16x8*>(&Bs[cur][(n * 16 + l15) * 32 + l4 * 8]);
#pragma unroll
    for (int m = 0; m < 2; ++m)
#pragma unroll
      for (int n = 0; n < 4; ++n)
        acc[m][n] = __builtin_amdgcn_mfma_f32_16x16x32_bf16(af[m], bfr[n], acc[m][n], 0, 0, 0);
    __syncthreads();
  }

  float bj[4];
#pragma unroll
  for (int n = 0; n < 4; ++n) bj[n] = bias[n0 + n * 16 + l15];
#pragma unroll
  for (int m = 0; m < 2; ++m)
#pragma unroll
    for (int n = 0; n < 4; ++n) {
      const int col = n0 + n * 16 + l15;
#pragma unroll
      for (int r = 0; r < 4; ++r) {
        const int row = m0 + w * 32 + m * 16 + l4 * 4 + r;
        C[(size_t)row * NEMB + col] = acc[m][n][r] + bj[n];
      }
    }
}

// ---------------------------------------------------------------------------
// MFMA flash attention v4: 32x32x16 MFMAs (2x FLOP per LDS byte vs 16x16x32).
// 4 waves (256 thr), QBLK=128 (32 q-rows/wave), KVBLK=64, dbuf K/Vt, 1 barrier.
// C-layout (m74/m101-verified): col=lane&31, row=(reg&3)+8*(reg>>2)+4*(lane>>5).
// A/B frags loaded as paired 16B-contiguous slices (k-permutation cancels).
// Softmax: native v_exp_f32 via __builtin_amdgcn_exp2f (scale pre-folded).
// LDS 48KB -> 3 blocks/CU; grid 768 = 8 XCDs x 96, bijective chunk.
// ---------------------------------------------------------------------------
__global__ __launch_bounds__(256, 3) void attn_mfma(const short* __restrict__ qp, const short* __restrict__ kp,
                                                    const short* __restrict__ vp, short* __restrict__ ao) {
  __shared__ __align__(16) short Ks[2][64 * 64];
  __shared__ __align__(16) short Vt[2][64 * 64];
  __shared__ __align__(16) short Ps[4][32 * 64];
  const int tid = threadIdx.x, lane = tid & 63, w = tid >> 6;
  const int j = lane & 31, hi = lane >> 5;
  const int wg = blockIdx.x;
  const int nid = (wg & 7) * 96 + (wg >> 3);
  const int q0 = (nid & 15) * 128;
  const int bh = nid >> 4;
  const int b = bh / NH, h = bh - b * NH;
  const size_t abase = (size_t)b * SEQ * NEMB + h * HD;

  // Q frags: A[i=lane&31][k=(lane>>5)*8+e] per 16-k slice, global->reg once
  bf16x8 qf[4];
#pragma unroll
  for (int ks = 0; ks < 4; ++ks)
    qf[ks] = *reinterpret_cast<const bf16x8*>(
        &qp[abase + (size_t)(q0 + w * 32 + j) * NEMB + ks * 16 + hi * 8]);

  // V staging ids (all 256 threads): 32 kv-row-pairs x 8 d-units
  const int vkv2 = tid >> 3, vd8 = tid & 7;
  const int vu = vkv2 >> 2, vsub = vkv2 & 3;
  const int swq = swz(j);           // P-read row swizzle (i = j)

  // ---- prologue: stage tile 0 into buf 0 ----
#pragma unroll
  for (int p = 0; p < 2; ++p) {
    const int idx = tid + p * 256;          // 512 16B units; 8 per 128B row
    const int row = idx >> 3, u = idx & 7;
    g2l16(kp + abase + (size_t)row * NEMB + (u ^ swz(row)) * 8, &Ks[0][idx * 8]);
  }
  {
    const short* vr = vp + abase + (size_t)(vkv2 * 2) * NEMB + vd8 * 8;
    bf16x8 v0 = *reinterpret_cast<const bf16x8*>(vr);
    bf16x8 v1 = *reinterpret_cast<const bf16x8*>(vr + NEMB);
    u32x4 a0 = __builtin_bit_cast(u32x4, v0);
    u32x4 a1 = __builtin_bit_cast(u32x4, v1);
#pragma unroll
    for (int jj = 0; jj < 4; ++jj) {
      unsigned lo = __builtin_amdgcn_perm(a1[jj], a0[jj], 0x05040100u);
      unsigned hi2 = __builtin_amdgcn_perm(a1[jj], a0[jj], 0x07060302u);
      const int d0 = vd8 * 8 + jj * 2;
      *reinterpret_cast<unsigned*>(reinterpret_cast<char*>(Vt[0]) + d0 * 128 + (vu ^ swz(d0)) * 16 + vsub * 4) = lo;
      *reinterpret_cast<unsigned*>(reinterpret_cast<char*>(Vt[0]) + (d0 + 1) * 128 + (vu ^ swz(d0 + 1)) * 16 + vsub * 4) = hi2;
    }
  }
  __syncthreads();

  f32x16 o[2] = {};
  float lacc[16];
#pragma unroll
  for (int r = 0; r < 16; ++r) lacc[r] = 0.f;

  for (int kt = 0; kt < SEQ / 64; ++kt) {
    const int cur = kt & 1, nxt = cur ^ 1;
    const bool more = (kt + 1) < SEQ / 64;

    // ---- issue next tile's staging (hidden under this tile's compute) ----
    bf16x8 v0, v1;
    if (more) {
#pragma unroll
      for (int p = 0; p < 2; ++p) {
        const int idx = tid + p * 256;
        const int row = idx >> 3, u = idx & 7;
        g2l16(kp + abase + (size_t)((kt + 1) * 64 + row) * NEMB + (u ^ swz(row)) * 8,
              &Ks[nxt][idx * 8]);
      }
      const short* vr = vp + abase + (size_t)((kt + 1) * 64 + vkv2 * 2) * NEMB + vd8 * 8;
      v0 = *reinterpret_cast<const bf16x8*>(vr);
      v1 = *reinterpret_cast<const bf16x8*>(vr + NEMB);
    }

    // ---- S = Q K^T : 2 col-groups x 4 k-slices of 32x32x16 ----
    f32x16 sf[2];
#pragma unroll
    for (int cg = 0; cg < 2; ++cg) {
      f32x16 a = {};
      const int jk = cg * 32 + j;
      const int sw = swz(jk);
#pragma unroll
      for (int ks = 0; ks < 4; ++ks) {
        bf16x8 kf = *reinterpret_cast<const bf16x8*>(
            reinterpret_cast<char*>(Ks[cur]) + jk * 128 + (((ks << 1) + hi) ^ sw) * 16);
        a = __builtin_amdgcn_mfma_f32_32x32x16_bf16(qf[ks], kf, a, 0, 0, 0);
      }
      sf[cg] = a;
    }

    // ---- softmax: p = 2^S (v_exp_f32); P store at true (q,kv) w/ swizzle ----
#pragma unroll
    for (int cg = 0; cg < 2; ++cg) {
      const int kvu = cg * 4 + (j >> 3);
      const int kvl = j & 7;
#pragma unroll
      for (int r = 0; r < 16; ++r) {
        const float p = __builtin_amdgcn_exp2f(sf[cg][r]);
        lacc[r] += p;
        const int qr = (r & 3) + 8 * (r >> 2) + 4 * hi;
        Ps[w][qr * 64 + ((kvu ^ swz(qr)) << 3) + kvl] = f2bf(p);
      }
    }

    // ---- late Vt write for next tile ----
    if (more) {
      u32x4 a0 = __builtin_bit_cast(u32x4, v0);
      u32x4 a1 = __builtin_bit_cast(u32x4, v1);
#pragma unroll
      for (int jj = 0; jj < 4; ++jj) {
        unsigned lo = __builtin_amdgcn_perm(a1[jj], a0[jj], 0x05040100u);
        unsigned hi2 = __builtin_amdgcn_perm(a1[jj], a0[jj], 0x07060302u);
        const int d0 = vd8 * 8 + jj * 2;
        *reinterpret_cast<unsigned*>(reinterpret_cast<char*>(Vt[nxt]) + d0 * 128 + (vu ^ swz(d0)) * 16 + vsub * 4) = lo;
        *reinterpret_cast<unsigned*>(reinterpret_cast<char*>(Vt[nxt]) + (d0 + 1) * 128 + (vu ^ swz(d0 + 1)) * 16 + vsub * 4) = hi2;
      }
    }

    // ---- O += P V : P as A (i=q), V as B (j=d-col) ----
    bf16x8 pa[4];
#pragma unroll
    for (int ks = 0; ks < 4; ++ks)
      pa[ks] = *reinterpret_cast<const bf16x8*>(
          &Ps[w][j * 64 + ((((ks << 1) + hi) ^ swq) << 3)]);
#pragma unroll
    for (int dg = 0; dg < 2; ++dg) {
      const int jd = dg * 32 + j;
      const int sw = swz(jd);
#pragma unroll
      for (int ks = 0; ks < 4; ++ks) {
        bf16x8 vf = *reinterpret_cast<const bf16x8*>(
            reinterpret_cast<char*>(Vt[cur]) + jd * 128 + (((ks << 1) + hi) ^ sw) * 16);
        o[dg] = __builtin_amdgcn_mfma_f32_32x32x16_bf16(pa[ks], vf, o[dg], 0, 0, 0);
      }
    }
    __syncthreads();   // single drain+barrier per iter; buffers flip
  }

  // ---- row-sums across the 32 kv-lanes (xor bits 0..4 keep lane-half) ----
#pragma unroll
  for (int r = 0; r < 16; ++r) {
#pragma unroll
    for (int off = 1; off < 32; off <<= 1)
      lacc[r] += __shfl_xor(lacc[r], off, 64);
    lacc[r] = 1.f / lacc[r];
  }

#pragma unroll
  for (int dg = 0; dg < 2; ++dg)
#pragma unroll
    for (int r = 0; r < 16; ++r) {
      const int row = q0 + w * 32 + (r & 3) + 8 * (r >> 2) + 4 * hi;
      ao[abase + (size_t)row * NEMB + dg * 32 + j] = f2bf(o[dg][r] * lacc[r]);
    }
}

// ---------------------------------------------------------------------------
extern "C" void kernel_launch(void* const* d_in, const int* in_sizes, int n_in,
                              void* d_out, int out_size, void* d_ws, size_t ws_size,
                              hipStream_t stream) {
  const float* key   = (const float*)d_in[0];
  const float* query = (const float*)d_in[1];
  const float* value = (const float*)d_in[2];
  const float* Wk    = (const float*)d_in[3];
  const float* bk    = (const float*)d_in[4];
  const float* Wq    = (const float*)d_in[5];
  const float* bq    = (const float*)d_in[6];
  const float* Wv    = (const float*)d_in[7];
  const float* bv    = (const float*)d_in[8];
  const float* Wfc   = (const float*)d_in[9];
  const float* bfc   = (const float*)d_in[10];

  const size_t P = (size_t)MTOT * NEMB;   // 6,291,456
  const size_t WSZ = (size_t)NEMB * NEMB; // 589,824
  short* ws  = (short*)d_ws;
  short* qb  = ws;
  short* kb2 = qb + P;
  short* vb2 = kb2 + P;
  short* wq  = vb2 + P;
  short* wk  = wq + WSZ;
  short* wv  = wk + WSZ;
  short* wf  = wv + WSZ;
  short* qpp = wf + WSZ;
  short* kpp = qpp + P;
  short* vpp = kpp + P;
  short* aop = vpp + P;

  cvt_all<<<dim3(P / 4 / 256, 7), 256, 0, stream>>>(
      query, key, value, Wq, Wk, Wv, Wfc, qb, kb2, vb2, wq, wk, wv, wf);

  gemm_qkv<<<dim3(MTOT / 128, NEMB / 128, 3), 256, 0, stream>>>(
      qb, kb2, vb2, wq, wk, wv, bq, bk, bv, qpp, kpp, vpp);

  attn_mfma<<<dim3(16 * BSZ * NH), 256, 0, stream>>>(qpp, kpp, vpp, aop);

  gemm_fc<<<dim3(MTOT / 128, NEMB / 64), 256, 0, stream>>>(aop, wf, bfc, (float*)d_out);
}